// Round 10
// baseline (242.332 us; speedup 1.0000x reference)
//
#include <hip/hip_runtime.h>

// GaLiTe attention layer, MI355X/gfx950 — all-fp32 (fp32 projections required:
// attn_den is a 256-term cancellation sum; bf16 decorrelates it — R2/R3).
// Shapes: T=64 B=16 DIM=512 H=8 Dh=64 ETA=4 FD=256.
// d_out = fp32 [ output(64*16*512) | kv_last(16*8*256*64) | nm_last(16*8*256) ].
//
// R10 = R9 + XCD-L2-locality swizzles (wg_id % 8 ~ XCD heuristic):
//  - proj: 1D grid, id = z + 8*(m + 16*n) -> XCD = z; X+W (3 MB) per L2.
//  - gate: grid (8 h, 1024 rows) -> writer XCD = h.
//  - scan4: blk = s*128 + bh -> all 8 d-splits of bh on XCD bh%8 = h
//    (matches gate's writer XCD; R9's FETCH=120 MB was x8 cross-XCD refetch).

#define T_N   64
#define B_N   16
#define DIM_N 512
#define H_N   8
#define DH_N  64
#define ETA_N 4
#define FD_N  256

#define OUT_ELEMS   524288   // T*B*DIM
#define KV_ELEMS    2097152  // B*H*FD*Dh

__device__ __forceinline__ float sigmoidf_(float x) {
    return 1.0f / (1.0f + __expf(-x));
}

// ---------------------------------------------------------------------------
// fp32 SGEMM (R8 body, block indices passed in): 64x64 tile, BK=16, 4x4 micro,
// double-buffered LDS (1 barrier/tile), LDS stride 68 (conflict-free).
// ---------------------------------------------------------------------------
__device__ __forceinline__ void gemm64_db(const float* __restrict__ A,
                                          const float* __restrict__ W,
                                          const float* __restrict__ bias,
                                          float* __restrict__ C, int N,
                                          int mb, int nb) {
    const int nbase = nb * 64;
    if (nbase >= N) return;

    __shared__ float As[2][16][68];
    __shared__ float Bs[2][16][68];

    const int tid = threadIdx.x;
    const int mbase = mb * 64;
    const int tx = tid & 15;
    const int ty = tid >> 4;
    const int sr = tid >> 2;
    const int sk = (tid & 3) << 2;
    const bool wok = (nbase + sr) < N;

    const float* Ap = A + (size_t)(mbase + sr) * 512 + sk;
    const float* Wp = W + (size_t)(nbase + sr) * 512 + sk;

    float4 av = *(const float4*)Ap;
    float4 wv = wok ? *(const float4*)Wp : make_float4(0.f, 0.f, 0.f, 0.f);
    As[0][sk + 0][sr] = av.x; As[0][sk + 1][sr] = av.y;
    As[0][sk + 2][sr] = av.z; As[0][sk + 3][sr] = av.w;
    Bs[0][sk + 0][sr] = wv.x; Bs[0][sk + 1][sr] = wv.y;
    Bs[0][sk + 2][sr] = wv.z; Bs[0][sk + 3][sr] = wv.w;

    float acc[4][4];
    #pragma unroll
    for (int i = 0; i < 4; ++i)
        #pragma unroll
        for (int j = 0; j < 4; ++j) acc[i][j] = 0.f;

    for (int k0 = 0; k0 < 512; k0 += 16) {
        const int buf = (k0 >> 4) & 1;
        __syncthreads();
        const bool more = (k0 + 16) < 512;
        if (more) {
            av = *(const float4*)(Ap + k0 + 16);
            wv = wok ? *(const float4*)(Wp + k0 + 16) : make_float4(0.f, 0.f, 0.f, 0.f);
        }
        #pragma unroll
        for (int k = 0; k < 16; ++k) {
            float4 a  = *(const float4*)&As[buf][k][ty << 2];
            float4 bq = *(const float4*)&Bs[buf][k][tx << 2];
            float ar[4] = {a.x, a.y, a.z, a.w};
            float br[4] = {bq.x, bq.y, bq.z, bq.w};
            #pragma unroll
            for (int i = 0; i < 4; ++i)
                #pragma unroll
                for (int j = 0; j < 4; ++j)
                    acc[i][j] = fmaf(ar[i], br[j], acc[i][j]);
        }
        if (more) {
            const int nbuf = buf ^ 1;
            As[nbuf][sk + 0][sr] = av.x; As[nbuf][sk + 1][sr] = av.y;
            As[nbuf][sk + 2][sr] = av.z; As[nbuf][sk + 3][sr] = av.w;
            Bs[nbuf][sk + 0][sr] = wv.x; Bs[nbuf][sk + 1][sr] = wv.y;
            Bs[nbuf][sk + 2][sr] = wv.z; Bs[nbuf][sk + 3][sr] = wv.w;
        }
    }

    #pragma unroll
    for (int i = 0; i < 4; ++i) {
        const int m = mbase + (ty << 2) + i;
        #pragma unroll
        for (int j = 0; j < 4; ++j) {
            const int n = nbase + (tx << 2) + j;
            if (n < N) {
                float v = acc[i][j];
                if (bias) v += bias[n];
                C[(size_t)m * N + n] = v;
            }
        }
    }
}

struct ProjW {
    const float* W[8];
    float*       D[8];
};

// 1D grid 1024: id = z + 8*(m + 16*n); XCD = id%8 = z (one projection per XCD,
// X 2MB + W 1MB working set per L2). z<5: N=512; z>=5: N=32 (n>0 returns).
__global__ __launch_bounds__(256) void proj_kernel(const float* __restrict__ X, ProjW a) {
    const int id = blockIdx.x;
    const int z = id & 7;
    const int rem = id >> 3;
    const int m = rem & 15;
    const int n = rem >> 4;
    const int N = (z < 5) ? 512 : 32;
    gemm64_db(X, a.W[z], nullptr, a.D[z], N, m, n);
}

// grid (16,8): out = attn @ Wo^T + bo
__global__ __launch_bounds__(256) void out_gemm_kernel(const float* __restrict__ A,
                                                       const float* __restrict__ W,
                                                       const float* __restrict__ bias,
                                                       float* __restrict__ C) {
    gemm64_db(A, W, bias, C, 512, blockIdx.x, blockIdx.y);
}

// ---------------------------------------------------------------------------
// gate_kernel: precompute disc/gk/phiq (per t,b,h,D) and gv (per t,b,h,d).
// grid (8 h, 1024 rows) -> wg id % 8 = h: writes land in XCD h's L2,
// matching scan4's reader XCD. Layout: [(row*8+h)*256 + D].
// ---------------------------------------------------------------------------
__global__ __launch_bounds__(256) void gate_kernel(
    const float* __restrict__ qb,  const float* __restrict__ kb,
    const float* __restrict__ vb,  const float* __restrict__ bb,
    const float* __restrict__ gb,  const float* __restrict__ p1b,
    const float* __restrict__ p2b, const float* __restrict__ p3b,
    const int* __restrict__ term,
    float* __restrict__ disc_g, float* __restrict__ gk_g,
    float* __restrict__ phiq_g, float* __restrict__ gv_g) {
    const int h = blockIdx.x;
    const int row = blockIdx.y;        // t*16 + b
    const int D = threadIdx.x;
    const int e = D >> 6, di = D & 63;
    const size_t base = (size_t)row * 512 + h * 64;
    const size_t pb = (size_t)row * 32 + h * 4;

    float q = qb[base + di], k = kb[base + di], g = gb[base + di];
    float p1 = p1b[pb + e], p2 = p2b[pb + e], p3 = p3b[pb + e];
    float mask = 1.0f - (float)term[row];
    float gf = sigmoidf_(p3) * sigmoidf_(g);

    const size_t o = ((size_t)row * 8 + h) * 256 + D;
    disc_g[o] = (1.0f - gf) * mask;
    gk_g[o]   = fmaxf(p1, 0.f) * k * gf;
    phiq_g[o] = fmaxf(p2, 0.f) * q;
    if (D < 64)
        gv_g[((size_t)row * 8 + h) * 64 + D] = vb[base + D] * sigmoidf_(bb[base + D]);
}

// ---------------------------------------------------------------------------
// scan4: d-split x8, precomputed gating. Grid 1024: blk = s*128 + bh
// (XCD = blk%8 = bh%8 = h -> all 8 splits of a bh share one XCD's L2;
// per-XCD gating working set 3 MB < 4 MB L2).
// Block 256 thr = 4 independent waves; wave w: d-cols dw = s*8 + w*2.
// Lane l owns D = 4l..4l+4: kv[j][c] = kv[4l+j][dw+c], nm[j] = nm[4l+j].
// ---------------------------------------------------------------------------
__global__ __launch_bounds__(256) void scan4_kernel(
    const float* __restrict__ disc_g, const float* __restrict__ gk_g,
    const float* __restrict__ phiq_g, const float* __restrict__ gv_g,
    float* __restrict__ vb /* attn out */,
    const float* __restrict__ kv0, const float* __restrict__ nm0,
    float* __restrict__ dout) {
    const int blk = blockIdx.x;       // 1024 = 8 splits x 128 bh
    const int bh = blk & 127;
    const int s  = blk >> 7;
    const int b  = bh >> 3;
    const int h  = bh & 7;
    const int tid = threadIdx.x;
    const int w = tid >> 6;
    const int l = tid & 63;
    const int dw = s * 8 + w * 2;     // wave's 2 d-cols
    const int D0 = l << 2;

    float kv[4][2];
    float nm[4];
    const size_t kvoff = ((size_t)bh * 256 + D0) * 64 + dw;
    #pragma unroll
    for (int j = 0; j < 4; ++j) {
        float2 r = *(const float2*)(kv0 + kvoff + (size_t)j * 64);
        kv[j][0] = r.x; kv[j][1] = r.y;
    }
    {
        float4 n4 = *(const float4*)(nm0 + (size_t)bh * 256 + D0);
        nm[0] = n4.x; nm[1] = n4.y; nm[2] = n4.z; nm[3] = n4.w;
    }

    // preload t=0
    float4 cd, cgk, cph; float2 cgv;
    {
        const size_t go = ((size_t)b * 8 + h) * 256 + D0;
        const size_t gvo = ((size_t)b * 8 + h) * 64 + dw;
        cd  = *(const float4*)(disc_g + go);
        cgk = *(const float4*)(gk_g + go);
        cph = *(const float4*)(phiq_g + go);
        cgv = *(const float2*)(gv_g + gvo);
    }

    for (int t = 0; t < T_N; ++t) {
        const int row = t * B_N + b;
        const size_t base = (size_t)row * 512 + h * 64;

        // prefetch t+1
        float4 nd = {}, ngk = {}, nph = {}; float2 ngv = {};
        if (t + 1 < T_N) {
            const size_t go2 = ((size_t)(row + B_N) * 8 + h) * 256 + D0;
            const size_t gvo2 = ((size_t)(row + B_N) * 8 + h) * 64 + dw;
            nd  = *(const float4*)(disc_g + go2);
            ngk = *(const float4*)(gk_g + go2);
            nph = *(const float4*)(phiq_g + go2);
            ngv = *(const float2*)(gv_g + gvo2);
        }

        const float dj[4]  = {cd.x, cd.y, cd.z, cd.w};
        const float gkj[4] = {cgk.x, cgk.y, cgk.z, cgk.w};
        const float phj[4] = {cph.x, cph.y, cph.z, cph.w};

        float den = 0.f, n0 = 0.f, n1 = 0.f;
        #pragma unroll
        for (int j = 0; j < 4; ++j) {
            nm[j] = dj[j] * nm[j] + gkj[j];
            den = fmaf(phj[j], nm[j], den);
            kv[j][0] = dj[j] * kv[j][0] + gkj[j] * cgv.x; n0 = fmaf(phj[j], kv[j][0], n0);
            kv[j][1] = dj[j] * kv[j][1] + gkj[j] * cgv.y; n1 = fmaf(phj[j], kv[j][1], n1);
        }

        #pragma unroll
        for (int ofs = 1; ofs < 64; ofs <<= 1) {
            n0  += __shfl_xor(n0, ofs);
            n1  += __shfl_xor(n1, ofs);
            den += __shfl_xor(den, ofs);
        }

        if (l < 2) {
            const float num = (l == 0) ? n0 : n1;
            vb[base + dw + l] = num / (den + 1e-6f);
        }

        cd = nd; cgk = ngk; cph = nph; cgv = ngv;
    }

    // final states
    {
        float* kp = dout + OUT_ELEMS + kvoff;
        #pragma unroll
        for (int j = 0; j < 4; ++j)
            *(float2*)(kp + (size_t)j * 64) = make_float2(kv[j][0], kv[j][1]);
        if (s == 0 && w == 0)
            *(float4*)(dout + OUT_ELEMS + KV_ELEMS + (size_t)bh * 256 + D0) =
                make_float4(nm[0], nm[1], nm[2], nm[3]);
    }
}

// ---------------------------------------------------------------------------
// Fallback scan (R7, proven): used when ws_size < 38.1 MB.
// ---------------------------------------------------------------------------
__global__ __launch_bounds__(256) void scan_kernel(
    const float* __restrict__ qb,  const float* __restrict__ kb,
    float* vb, const float* __restrict__ bb,
    const float* __restrict__ gb,  const float* __restrict__ p1b,
    const float* __restrict__ p2b, const float* __restrict__ p3b,
    const int* __restrict__ term,
    const float* __restrict__ kv0, const float* __restrict__ nm0,
    float* __restrict__ dout) {
    const int blk = blockIdx.x;
    const int bh = blk >> 2;
    const int s  = blk & 3;
    const int b  = bh >> 3;
    const int h  = bh & 7;
    const int tid = threadIdx.x;
    const int w = tid >> 6;
    const int l = tid & 63;
    const int dw  = s * 16 + w * 4;
    const int D0  = l << 2;
    const int eta = l >> 4;
    const int di0 = (l & 15) << 2;

    float kv[4][4];
    float nm[4];
    const size_t kvoff = ((size_t)bh * 256 + D0) * 64 + dw;
    {
        const float* kp = kv0 + kvoff;
        #pragma unroll
        for (int j = 0; j < 4; ++j) {
            float4 r = *(const float4*)(kp + (size_t)j * 64);
            kv[j][0] = r.x; kv[j][1] = r.y; kv[j][2] = r.z; kv[j][3] = r.w;
        }
        float4 n4 = *(const float4*)(nm0 + (size_t)bh * 256 + D0);
        nm[0] = n4.x; nm[1] = n4.y; nm[2] = n4.z; nm[3] = n4.w;
    }

    float4 cq, ck, cg, cv, cb;
    float cp1, cp2, cp3, cmask;
    {
        const size_t base = (size_t)b * 512 + h * 64;
        const size_t pb = (size_t)b * 32 + h * 4;
        cq = *(const float4*)(qb + base + di0);
        ck = *(const float4*)(kb + base + di0);
        cg = *(const float4*)(gb + base + di0);
        cv = *(const float4*)(vb + base + dw);
        cb = *(const float4*)(bb + base + dw);
        cp1 = p1b[pb + eta]; cp2 = p2b[pb + eta]; cp3 = p3b[pb + eta];
        cmask = 1.0f - (float)term[b];
    }

    for (int t = 0; t < T_N; ++t) {
        const int row = t * B_N + b;
        const size_t base = (size_t)row * 512 + h * 64;

        float4 nq = {}, nk = {}, ng = {}, nv = {}, nb4 = {};
        float np1 = 0.f, np2 = 0.f, np3 = 0.f, nmask = 0.f;
        if (t + 1 < T_N) {
            const int r2 = row + B_N;
            const size_t b2 = (size_t)r2 * 512 + h * 64;
            const size_t pb2 = (size_t)r2 * 32 + h * 4;
            nq = *(const float4*)(qb + b2 + di0);
            nk = *(const float4*)(kb + b2 + di0);
            ng = *(const float4*)(gb + b2 + di0);
            nv = *(const float4*)(vb + b2 + dw);
            nb4 = *(const float4*)(bb + b2 + dw);
            np1 = p1b[pb2 + eta]; np2 = p2b[pb2 + eta]; np3 = p3b[pb2 + eta];
            nmask = 1.0f - (float)term[r2];
        }

        const float gv0 = cv.x * sigmoidf_(cb.x);
        const float gv1 = cv.y * sigmoidf_(cb.y);
        const float gv2 = cv.z * sigmoidf_(cb.z);
        const float gv3 = cv.w * sigmoidf_(cb.w);

        const float p1r = fmaxf(cp1, 0.f);
        const float p2r = fmaxf(cp2, 0.f);
        const float sp3 = sigmoidf_(cp3);

        const float qj[4] = {cq.x, cq.y, cq.z, cq.w};
        const float kj[4] = {ck.x, ck.y, ck.z, ck.w};
        const float gj[4] = {cg.x, cg.y, cg.z, cg.w};

        float denp = 0.f, n0 = 0.f, n1 = 0.f, n2 = 0.f, n3 = 0.f;
        #pragma unroll
        for (int j = 0; j < 4; ++j) {
            const float gf   = sp3 * sigmoidf_(gj[j]);
            const float phiq = p2r * qj[j];
            const float gk   = p1r * kj[j] * gf;
            const float disc = (1.0f - gf) * cmask;
            nm[j] = disc * nm[j] + gk;
            denp = fmaf(phiq, nm[j], denp);
            kv[j][0] = disc * kv[j][0] + gk * gv0; n0 = fmaf(phiq, kv[j][0], n0);
            kv[j][1] = disc * kv[j][1] + gk * gv1; n1 = fmaf(phiq, kv[j][1], n1);
            kv[j][2] = disc * kv[j][2] + gk * gv2; n2 = fmaf(phiq, kv[j][2], n2);
            kv[j][3] = disc * kv[j][3] + gk * gv3; n3 = fmaf(phiq, kv[j][3], n3);
        }

        #pragma unroll
        for (int ofs = 1; ofs < 64; ofs <<= 1) {
            n0   += __shfl_xor(n0, ofs);
            n1   += __shfl_xor(n1, ofs);
            n2   += __shfl_xor(n2, ofs);
            n3   += __shfl_xor(n3, ofs);
            denp += __shfl_xor(denp, ofs);
        }

        if (l < 4) {
            const float num = (l == 0) ? n0 : (l == 1) ? n1 : (l == 2) ? n2 : n3;
            vb[base + dw + l] = num / (denp + 1e-6f);
        }

        cq = nq; ck = nk; cg = ng; cv = nv; cb = nb4;
        cp1 = np1; cp2 = np2; cp3 = np3; cmask = nmask;
    }

    {
        float* kp = dout + OUT_ELEMS + kvoff;
        #pragma unroll
        for (int j = 0; j < 4; ++j)
            *(float4*)(kp + (size_t)j * 64) = make_float4(kv[j][0], kv[j][1], kv[j][2], kv[j][3]);
        if (s == 0 && w == 0)
            *(float4*)(dout + OUT_ELEMS + KV_ELEMS + (size_t)bh * 256 + D0) =
                make_float4(nm[0], nm[1], nm[2], nm[3]);
    }
}

// ---------------------------------------------------------------------------
extern "C" void kernel_launch(void* const* d_in, const int* in_sizes, int n_in,
                              void* d_out, int out_size, void* d_ws, size_t ws_size,
                              hipStream_t stream) {
    (void)in_sizes; (void)n_in; (void)out_size;

    const float* X    = (const float*)d_in[0];
    const int*   term = (const int*)  d_in[1];
    const float* kv0  = (const float*)d_in[2];
    const float* nm0  = (const float*)d_in[3];
    const float* Wq   = (const float*)d_in[4];
    const float* Wk   = (const float*)d_in[5];
    const float* Wv   = (const float*)d_in[6];
    const float* Wb   = (const float*)d_in[7];
    const float* Wg   = (const float*)d_in[8];
    const float* Wp1  = (const float*)d_in[9];
    const float* Wp2  = (const float*)d_in[10];
    const float* Wp3  = (const float*)d_in[11];
    const float* Wo   = (const float*)d_in[12];
    const float* bo   = (const float*)d_in[13];

    float* out = (float*)d_out;

    // ---- base workspace (10.88 MB) ----
    float* qb  = (float*)d_ws;            // 1024x512
    float* kb  = qb  + 524288;
    float* vb  = kb  + 524288;            // v, later attn
    float* bb  = vb  + 524288;
    float* gb  = bb  + 524288;
    float* p1b = gb  + 524288;            // 1024x32
    float* p2b = p1b + 32768;
    float* p3b = p2b + 32768;
    float* extra = p3b + 32768;

    // ---- big path extras: disc/gk/phiq (3 x 2M) + gv (0.5M) = 26 MB ----
    float* disc_g = extra;
    float* gk_g   = disc_g + 2097152;
    float* phiq_g = gk_g   + 2097152;
    float* gv_g   = phiq_g + 2097152;
    const size_t need_bytes = (size_t)(2719744 + 3 * 2097152 + 524288) * 4;  // 38.1 MB
    const bool big = ws_size >= need_bytes;   // R9: big path taken -> ws >= 38.1 MB

    ProjW pa;
    pa.W[0] = Wq;  pa.W[1] = Wk;  pa.W[2] = Wv;  pa.W[3] = Wb;
    pa.W[4] = Wg;  pa.W[5] = Wp1; pa.W[6] = Wp2; pa.W[7] = Wp3;
    pa.D[0] = qb;  pa.D[1] = kb;  pa.D[2] = vb;  pa.D[3] = bb;
    pa.D[4] = gb;  pa.D[5] = p1b; pa.D[6] = p2b; pa.D[7] = p3b;
    proj_kernel<<<1024, 256, 0, stream>>>(X, pa);

    if (big) {
        gate_kernel<<<dim3(8, 1024), 256, 0, stream>>>(qb, kb, vb, bb, gb,
                                                       p1b, p2b, p3b, term,
                                                       disc_g, gk_g, phiq_g, gv_g);
        scan4_kernel<<<1024, 256, 0, stream>>>(disc_g, gk_g, phiq_g, gv_g,
                                               vb, kv0, nm0, out);
    } else {
        scan_kernel<<<512, 256, 0, stream>>>(qb, kb, vb, bb, gb, p1b, p2b, p3b,
                                             term, kv0, nm0, out);
    }

    out_gemm_kernel<<<dim3(16, 8), 256, 0, stream>>>(vb, Wo, bo, out);
}